// Round 4
// baseline (134.837 us; speedup 1.0000x reference)
//
#include <hip/hip_runtime.h>
#include <hip/hip_bf16.h>

#define N_ROWS 4096
#define DIM 512
#define TWO_N 8192
#define NT2   32                 // 8192 / 256
#define NTRI2 (NT2 * (NT2 + 1) / 2)   // 528 upper-tri blocks

typedef __bf16 bf16x8 __attribute__((ext_vector_type(8)));
typedef float  f32x4  __attribute__((ext_vector_type(4)));

// ---------------------------------------------------------------------------
// round-to-nearest-even float -> bf16 bits
__device__ inline unsigned short f2bf(float f) {
    unsigned int u = __float_as_uint(f);
    u += 0x7fffu + ((u >> 16) & 1u);
    return (unsigned short)(u >> 16);
}

// async global -> LDS, 16 bytes per lane (wave-uniform LDS base + lane*16)
__device__ inline void g2l16(const void* g, void* l) {
    __builtin_amdgcn_global_load_lds(
        (const __attribute__((address_space(1))) void*)g,
        (__attribute__((address_space(3))) void*)l,
        16, 0, 0);
}

// ---------------------------------------------------------------------------
// Kernel 1: normalize rows of emb_i / emb_j, emit bf16 z [2N][D], pos[N],
// zero denom[2N] and out[0]. One block (256 thr) per row pair.
__global__ void normalize_kernel(const float* __restrict__ ei,
                                 const float* __restrict__ ej,
                                 unsigned short* __restrict__ zb,
                                 float* __restrict__ pos,
                                 float* __restrict__ denom,
                                 float* __restrict__ out) {
    int r = blockIdx.x;          // 0..4095
    int t = threadIdx.x;         // 0..255, each handles 2 dims via float2
    const float2 vi = ((const float2*)(ei + (size_t)r * DIM))[t];
    const float2 vj = ((const float2*)(ej + (size_t)r * DIM))[t];
    float si  = vi.x * vi.x + vi.y * vi.y;
    float sj  = vj.x * vj.x + vj.y * vj.y;
    float sij = vi.x * vj.x + vi.y * vj.y;

    for (int o = 32; o; o >>= 1) {
        si  += __shfl_down(si, o);
        sj  += __shfl_down(sj, o);
        sij += __shfl_down(sij, o);
    }
    __shared__ float red[3][4];
    int wave = t >> 6, lane = t & 63;
    if (lane == 0) { red[0][wave] = si; red[1][wave] = sj; red[2][wave] = sij; }
    __syncthreads();
    si  = red[0][0] + red[0][1] + red[0][2] + red[0][3];
    sj  = red[1][0] + red[1][1] + red[1][2] + red[1][3];
    sij = red[2][0] + red[2][1] + red[2][2] + red[2][3];

    float rni = 1.0f / fmaxf(sqrtf(si), 1e-12f);
    float rnj = 1.0f / fmaxf(sqrtf(sj), 1e-12f);
    if (t == 0) {
        pos[r] = sij * rni * rnj;
        denom[r] = 0.0f;
        denom[r + N_ROWS] = 0.0f;
        if (r == 0) out[0] = 0.0f;   // accumulated by loss_kernel (stream-ordered)
    }
    ushort2 zi2 = make_ushort2(f2bf(vi.x * rni), f2bf(vi.y * rni));
    ushort2 zj2 = make_ushort2(f2bf(vj.x * rnj), f2bf(vj.y * rnj));
    ((ushort2*)(zb + (size_t)r * DIM))[t] = zi2;
    ((ushort2*)(zb + (size_t)(r + N_ROWS) * DIM))[t] = zj2;
}

// ---------------------------------------------------------------------------
// Kernel 2 (v5): upper-triangular 256x256-tile bf16 MFMA GEMM of z·zT.
// 8 waves (2M x 4N), BK=64, double-buffered 128KB LDS. Per K-tile: two
// phases {prefetch 4 g2l16 of tile t+1 | 12 ds_read | 32 MFMA}, then ONE
// vmcnt(0)+s_barrier per tile -- prefetch loads get 300-600cy of MFMA
// cover before their drain (v4 had ~0), and MFMA-per-barrier is 4x v4.
//
// LDS layout identical to v4 (proven 0 bank conflicts): row = 64 ushort
// = 8 granules of 16B; phys granule = logical ^ (row&7); staged with
// pre-swizzled global source, linear LDS dest.
__global__ __launch_bounds__(512, 2) void gemm_exp_kernel(
        const unsigned short* __restrict__ zb,
        float* __restrict__ denom) {
    // ---- linear index -> (by, bx), by <= bx, row-major over by ----
    const int t = blockIdx.x;
    int by = (int)(0.5f * (2.0f * NT2 + 1.0f -
              sqrtf((2.0f * NT2 + 1.0f) * (2.0f * NT2 + 1.0f) - 8.0f * t)));
    while ((by + 1) * NT2 - ((by + 1) * by) / 2 <= t) ++by;
    while (by * NT2 - (by * (by - 1)) / 2 > t) --by;
    const int bx = by + (t - (by * NT2 - (by * (by - 1)) / 2));

    const int rb = by * 256;             // row tile base
    const int cb = bx * 256;             // col tile base
    const bool diag = (rb == cb);

    const int tid  = threadIdx.x;
    const int wave = tid >> 6;           // 0..7
    const int lane = tid & 63;
    const int quad = lane >> 4;          // 0..3
    const int m    = lane & 15;          // 0..15
    const int wm   = (wave >> 2) * 128;  // wave row offset in tile (0/128)
    const int wn   = (wave & 3) * 64;    // wave col offset (0/64/128/192)

    __shared__ __align__(16) unsigned short As[2][256 * 64];
    __shared__ __align__(16) unsigned short Bs[2][256 * 64];

    f32x4 acc[8][4];
    #pragma unroll
    for (int i = 0; i < 8; ++i)
        #pragma unroll
        for (int j = 0; j < 4; ++j)
            #pragma unroll
            for (int r = 0; r < 4; ++r) acc[i][j][r] = 0.0f;

    // staging: chunk = 1KB = 8 rows x 8 granules; 32 chunks per matrix;
    // wave w stages chunks 4w..4w+3 (2 per phase). Lane l -> byte l*16 of
    // chunk: row c*8+(l>>3), phys slot l&7, holding global granule
    // (l&7)^(l>>3) -> phys slot s at row r holds logical granule s^(r&7).
    const int srow8 = lane >> 3;
    const int sk    = (((lane & 7) ^ srow8) * 8);

    // prologue: stage all of tile 0
    #pragma unroll
    for (int cc = 0; cc < 4; ++cc) {
        int c = 4 * wave + cc;
        int row = c * 8 + srow8;
        g2l16(zb + (size_t)(rb + row) * DIM + sk, &As[0][c * 512]);
        g2l16(zb + (size_t)(cb + row) * DIM + sk, &Bs[0][c * 512]);
    }
    asm volatile("s_waitcnt vmcnt(0)" ::: "memory");
    __builtin_amdgcn_s_barrier();

    #pragma unroll 1
    for (int it = 0; it < DIM / 64; ++it) {
        const int cur = it & 1;
        const int nxt = cur ^ 1;
        const int k1  = (it + 1) * 64;

        #pragma unroll
        for (int h = 0; h < 2; ++h) {
            // prefetch half of tile it+1 (2 A-chunks + 2 B-chunks)
            if (it < DIM / 64 - 1) {
                #pragma unroll
                for (int cc = 0; cc < 2; ++cc) {
                    int c = 4 * wave + 2 * h + cc;
                    int row = c * 8 + srow8;
                    g2l16(zb + (size_t)(rb + row) * DIM + k1 + sk, &As[nxt][c * 512]);
                    g2l16(zb + (size_t)(cb + row) * DIM + k1 + sk, &Bs[nxt][c * 512]);
                }
            }
            // fragment reads for k-half h: logical granule (h*4+quad),
            // phys slot = granule ^ (row&7) = granule ^ (m&7)
            bf16x8 af[8], bfr[4];
            const int sl = ((((h << 2) | quad) ^ (m & 7)) * 8);
            #pragma unroll
            for (int i = 0; i < 8; ++i)
                af[i] = *(const bf16x8*)(&As[cur][(wm + i * 16 + m) * 64 + sl]);
            #pragma unroll
            for (int j = 0; j < 4; ++j)
                bfr[j] = *(const bf16x8*)(&Bs[cur][(wn + j * 16 + m) * 64 + sl]);

            asm volatile("s_waitcnt lgkmcnt(0)" ::: "memory");
            __builtin_amdgcn_sched_barrier(0);
            __builtin_amdgcn_s_setprio(1);
            #pragma unroll
            for (int i = 0; i < 8; ++i)
                #pragma unroll
                for (int j = 0; j < 4; ++j)
                    acc[i][j] = __builtin_amdgcn_mfma_f32_16x16x32_bf16(
                        af[i], bfr[j], acc[i][j], 0, 0, 0);
            __builtin_amdgcn_s_setprio(0);
        }
        // own 8 prefetch loads (issued 1-2 phases ago) done; barrier makes
        // ALL waves' loads visible and confirms everyone finished reading
        // buf[cur] -> next iter may read buf[nxt] and overwrite buf[cur].
        asm volatile("s_waitcnt vmcnt(0)" ::: "memory");
        __builtin_amdgcn_s_barrier();
    }

    // ---- epilogue: exp(2*sim), mask diag, row sums (+ col sums off-diag) ----
    // last s_barrier: all ds_reads complete -> safe to reuse As as scratch
    float* rs = (float*)&As[0][0];     // rowsum[256] | colsum[256]
    float* cs = rs + 256;
    if (tid < 256) { rs[tid] = 0.0f; cs[tid] = 0.0f; }
    __syncthreads();

    float colsum[4] = {0.0f, 0.0f, 0.0f, 0.0f};
    #pragma unroll
    for (int i = 0; i < 8; ++i) {
        #pragma unroll
        for (int r = 0; r < 4; ++r) {
            int lrow = wm + i * 16 + quad * 4 + r;    // local row 0..255
            int grow = rb + lrow;
            float s = 0.0f;
            #pragma unroll
            for (int j = 0; j < 4; ++j) {
                int gcol = cb + wn + j * 16 + m;
                float v  = __expf(2.0f * acc[i][j][r]);
                v = (grow == gcol) ? 0.0f : v;
                s += v;
                colsum[j] += v;
            }
            // sum across the 16 lanes of this quad-row group (bits 0..3)
            s += __shfl_xor(s, 1);
            s += __shfl_xor(s, 2);
            s += __shfl_xor(s, 4);
            s += __shfl_xor(s, 8);
            if (m == 0) atomicAdd(&rs[lrow], s);
        }
    }
    if (!diag) {
        #pragma unroll
        for (int j = 0; j < 4; ++j) {
            float s = colsum[j];       // this wave's 128 rows, col wn+j*16+m
            s += __shfl_xor(s, 16);    // combine across quads (rows)
            s += __shfl_xor(s, 32);
            if (quad == 0) atomicAdd(&cs[wn + j * 16 + m], s);
        }
    }
    __syncthreads();
    if (tid < 256) {
        atomicAdd(&denom[rb + tid], rs[tid]);
        if (!diag) atomicAdd(&denom[cb + tid], cs[tid]);
    }
}

// ---------------------------------------------------------------------------
// Kernel 3: loss += sum_r [ log(denom[r]) - 2*pos[r % N] ] / 2N.
// 32 blocks x 256 threads, one row each; per-block reduce + one atomic.
__global__ void loss_kernel(const float* __restrict__ pos,
                            const float* __restrict__ denom,
                            float* __restrict__ out) {
    int r = blockIdx.x * 256 + threadIdx.x;   // 0..8191
    float s = __logf(denom[r]) - 2.0f * pos[r & (N_ROWS - 1)];
    for (int o = 32; o; o >>= 1) s += __shfl_down(s, o);
    __shared__ float red[4];
    int t = threadIdx.x;
    if ((t & 63) == 0) red[t >> 6] = s;
    __syncthreads();
    if (t == 0)
        atomicAdd(out, (red[0] + red[1] + red[2] + red[3]) / (float)TWO_N);
}

// ---------------------------------------------------------------------------
extern "C" void kernel_launch(void* const* d_in, const int* in_sizes, int n_in,
                              void* d_out, int out_size, void* d_ws, size_t ws_size,
                              hipStream_t stream) {
    const float* ei = (const float*)d_in[0];
    const float* ej = (const float*)d_in[1];

    // ws layout: zb (bf16, 2N*D = 8 MB) | pos (N f32) | denom (2N f32)
    unsigned short* zb  = (unsigned short*)d_ws;
    float* pos   = (float*)((char*)d_ws + (size_t)TWO_N * DIM * sizeof(unsigned short));
    float* denom = pos + N_ROWS;
    float* out   = (float*)d_out;

    normalize_kernel<<<N_ROWS, 256, 0, stream>>>(ei, ej, zb, pos, denom, out);
    gemm_exp_kernel<<<NTRI2, 512, 0, stream>>>(zb, denom);
    loss_kernel<<<TWO_N / 256, 256, 0, stream>>>(pos, denom, out);
}

// Round 5
// 130.203 us; speedup vs baseline: 1.0356x; 1.0356x over previous
//
#include <hip/hip_runtime.h>
#include <hip/hip_bf16.h>

#define N_ROWS 4096
#define DIM 512
#define TWO_N 8192
#define NT2   32                 // 8192 / 256
#define NTRI2 (NT2 * (NT2 + 1) / 2)   // 528 upper-tri blocks

typedef __bf16 bf16x8 __attribute__((ext_vector_type(8)));
typedef float  f32x4  __attribute__((ext_vector_type(4)));

// ---------------------------------------------------------------------------
// round-to-nearest-even float -> bf16 bits
__device__ inline unsigned short f2bf(float f) {
    unsigned int u = __float_as_uint(f);
    u += 0x7fffu + ((u >> 16) & 1u);
    return (unsigned short)(u >> 16);
}

// async global -> LDS, 16 bytes per lane (wave-uniform LDS base + lane*16)
__device__ inline void g2l16(const void* g, void* l) {
    __builtin_amdgcn_global_load_lds(
        (const __attribute__((address_space(1))) void*)g,
        (__attribute__((address_space(3))) void*)l,
        16, 0, 0);
}

// ---------------------------------------------------------------------------
// Kernel 1: normalize rows of emb_i / emb_j, emit bf16 z [2N][D], pos[N],
// zero denom[2N] and out[0]. One block (256 thr) per row pair.
__global__ void normalize_kernel(const float* __restrict__ ei,
                                 const float* __restrict__ ej,
                                 unsigned short* __restrict__ zb,
                                 float* __restrict__ pos,
                                 float* __restrict__ denom,
                                 float* __restrict__ out) {
    int r = blockIdx.x;          // 0..4095
    int t = threadIdx.x;         // 0..255, each handles 2 dims via float2
    const float2 vi = ((const float2*)(ei + (size_t)r * DIM))[t];
    const float2 vj = ((const float2*)(ej + (size_t)r * DIM))[t];
    float si  = vi.x * vi.x + vi.y * vi.y;
    float sj  = vj.x * vj.x + vj.y * vj.y;
    float sij = vi.x * vj.x + vi.y * vj.y;

    for (int o = 32; o; o >>= 1) {
        si  += __shfl_down(si, o);
        sj  += __shfl_down(sj, o);
        sij += __shfl_down(sij, o);
    }
    __shared__ float red[3][4];
    int wave = t >> 6, lane = t & 63;
    if (lane == 0) { red[0][wave] = si; red[1][wave] = sj; red[2][wave] = sij; }
    __syncthreads();
    si  = red[0][0] + red[0][1] + red[0][2] + red[0][3];
    sj  = red[1][0] + red[1][1] + red[1][2] + red[1][3];
    sij = red[2][0] + red[2][1] + red[2][2] + red[2][3];

    float rni = 1.0f / fmaxf(sqrtf(si), 1e-12f);
    float rnj = 1.0f / fmaxf(sqrtf(sj), 1e-12f);
    if (t == 0) {
        pos[r] = sij * rni * rnj;
        denom[r] = 0.0f;
        denom[r + N_ROWS] = 0.0f;
        if (r == 0) out[0] = 0.0f;   // accumulated by loss_kernel (stream-ordered)
    }
    ushort2 zi2 = make_ushort2(f2bf(vi.x * rni), f2bf(vi.y * rni));
    ushort2 zj2 = make_ushort2(f2bf(vj.x * rnj), f2bf(vj.y * rnj));
    ((ushort2*)(zb + (size_t)r * DIM))[t] = zi2;
    ((ushort2*)(zb + (size_t)(r + N_ROWS) * DIM))[t] = zj2;
}

// ---------------------------------------------------------------------------
// Kernel 2 (v6): 256x256-tile upper-tri GEMM, 8 waves (2Mx4N), BK=64.
//
// Phase-split pipeline (T3+T4+T5), quarter-tile ring staging:
//  * staging unit = quarter (64 rows x 64 K = 8KB = 1 g2l16/thread); two
//    8-slot LDS rings (A,B) of 8KB slots; stage at global phase f -> slot
//    f&7.  2 loads/thread/phase, lookahead 3-6 phases.
//  * phase top: s_waitcnt vmcnt(4) (NEVER 0 in main loop: newest 2 phases'
//    4 loads stay in flight) -> s_barrier -> ds_read -> stage-issue ->
//    lgkmcnt(0) -> 16 MFMA under setprio(1).
//  * per K-tile t (4 phases, qr=p>>1, qc=p&1): phase reads: 12/4/8/0
//    (B frags held in regs across the tile).
//  * slot-reuse and read-window safety hand-verified: every overwrite is
//    issued >= 1 barrier after the prior occupant's last ds_read.
//
// LDS granule swizzle (verified, 0 bank conflicts): row r of a quarter
// holds at phys 16B-slot s the logical granule s^(r&7); staged via
// pre-swizzled global source; read at slot ((k*4+quad)^(m&7)).
__global__ __launch_bounds__(512, 1) void gemm_exp_kernel(
        const unsigned short* __restrict__ zb,
        float* __restrict__ denom) {
    // ---- linear index -> (by, bx), by <= bx, row-major over by ----
    const int t0 = blockIdx.x;
    int by = (int)(0.5f * (2.0f * NT2 + 1.0f -
              sqrtf((2.0f * NT2 + 1.0f) * (2.0f * NT2 + 1.0f) - 8.0f * t0)));
    while ((by + 1) * NT2 - ((by + 1) * by) / 2 <= t0) ++by;
    while (by * NT2 - (by * (by - 1)) / 2 > t0) --by;
    const int bx = by + (t0 - (by * NT2 - (by * (by - 1)) / 2));

    const int rb = by * 256;             // row tile base
    const int cb = bx * 256;             // col tile base
    const bool diag = (rb == cb);

    const int tid  = threadIdx.x;
    const int wave = tid >> 6;           // 0..7
    const int lane = tid & 63;
    const int quad = lane >> 4;          // 0..3
    const int m    = lane & 15;          // 0..15
    const int wgrp = wave >> 2;          // 0/1: A row-half (rows 128*wgrp)
    const int qB   = wave & 3;           // B col-quarter (cols 64*qB)
    const int wm   = wgrp * 128;
    const int wn   = qB * 64;

    __shared__ __align__(16) unsigned short Aring[8][4096];  // 8 x 8KB
    __shared__ __align__(16) unsigned short Bring[8][4096];  // 8 x 8KB

    f32x4 acc[8][4];
    #pragma unroll
    for (int i = 0; i < 8; ++i)
        #pragma unroll
        for (int j = 0; j < 4; ++j)
            #pragma unroll
            for (int r = 0; r < 4; ++r) acc[i][j][r] = 0.0f;

    // staging: quarter = 64 rows x 64 cols; wave w covers rows 8w..8w+7;
    // lane l -> row 8w+(l>>3), phys slot l&7, source granule (l&7)^(l>>3).
    const int srow8 = lane >> 3;
    const int sk    = (((lane & 7) ^ srow8) * 8);

    auto stageA = [&](int slot, int tt, int qq) {
        const unsigned short* g = zb +
            (size_t)(rb + qq * 64 + wave * 8 + srow8) * DIM + tt * 64 + sk;
        g2l16(g, &Aring[slot][wave * 512]);
    };
    auto stageB = [&](int slot, int tt, int qq) {
        const unsigned short* g = zb +
            (size_t)(cb + qq * 64 + wave * 8 + srow8) * DIM + tt * 64 + sk;
        g2l16(g, &Bring[slot][wave * 512]);
    };

    // fragment byte offset within a quarter: row-frag fr (0..3), k-half k
    auto foff = [&](int fr, int k) {
        return (fr * 16 + m) * 64 + ((((k << 2) | quad) ^ (m & 7)) * 8);
    };

    // ---- prologue: 12 stages (6 virtual phases x 2), slots 2..7 ----
    stageA(2, 0, 0); stageB(2, 0, 0);
    stageA(3, 0, 2); stageB(3, 0, 1);
    stageA(4, 0, 1); stageB(4, 0, 2);
    stageA(5, 0, 3); stageB(5, 0, 3);
    stageA(6, 1, 0); stageB(6, 1, 0);
    stageA(7, 1, 2); stageB(7, 1, 1);

    #pragma unroll 1
    for (int t = 0; t < DIM / 64; ++t) {
        const int t4 = t * 4;
        // this wave's read slots for tile t
        const unsigned short* A0b = &Aring[(t4 + 2 + wgrp) & 7][0]; // quarter 2w+0
        const unsigned short* A1b = &Aring[(t4 + 4 + wgrp) & 7][0]; // quarter 2w+1
        const unsigned short* Bb  = &Bring[(t4 + 2 + qB) & 7][0];   // quarter qB

        bf16x8 a0[4][2], a1[4][2], b0[2][2], b1[2][2];

        // ================= phase 0 (qr=0, qc=0) =================
        asm volatile("s_waitcnt vmcnt(4)" ::: "memory");
        __builtin_amdgcn_s_barrier();
        #pragma unroll
        for (int ii = 0; ii < 4; ++ii) {
            a0[ii][0] = *(const bf16x8*)(A0b + foff(ii, 0));
            a0[ii][1] = *(const bf16x8*)(A0b + foff(ii, 1));
        }
        #pragma unroll
        for (int jj = 0; jj < 2; ++jj) {
            b0[jj][0] = *(const bf16x8*)(Bb + foff(jj, 0));
            b0[jj][1] = *(const bf16x8*)(Bb + foff(jj, 1));
        }
        if (t < 7) { stageA(t4 & 7, t + 1, 1); stageB(t4 & 7, t + 1, 2); }
        asm volatile("s_waitcnt lgkmcnt(0)" ::: "memory");
        __builtin_amdgcn_sched_barrier(0);
        __builtin_amdgcn_s_setprio(1);
        #pragma unroll
        for (int ii = 0; ii < 4; ++ii)
            #pragma unroll
            for (int jj = 0; jj < 2; ++jj)
                #pragma unroll
                for (int k = 0; k < 2; ++k)
                    acc[ii][jj] = __builtin_amdgcn_mfma_f32_16x16x32_bf16(
                        a0[ii][k], b0[jj][k], acc[ii][jj], 0, 0, 0);
        __builtin_amdgcn_s_setprio(0);

        // ================= phase 1 (qr=0, qc=1) =================
        asm volatile("s_waitcnt vmcnt(4)" ::: "memory");
        __builtin_amdgcn_s_barrier();
        #pragma unroll
        for (int jj = 0; jj < 2; ++jj) {
            b1[jj][0] = *(const bf16x8*)(Bb + foff(2 + jj, 0));
            b1[jj][1] = *(const bf16x8*)(Bb + foff(2 + jj, 1));
        }
        if (t < 7) { stageA((t4 + 1) & 7, t + 1, 3); stageB((t4 + 1) & 7, t + 1, 3); }
        asm volatile("s_waitcnt lgkmcnt(0)" ::: "memory");
        __builtin_amdgcn_sched_barrier(0);
        __builtin_amdgcn_s_setprio(1);
        #pragma unroll
        for (int ii = 0; ii < 4; ++ii)
            #pragma unroll
            for (int jj = 0; jj < 2; ++jj)
                #pragma unroll
                for (int k = 0; k < 2; ++k)
                    acc[ii][2 + jj] = __builtin_amdgcn_mfma_f32_16x16x32_bf16(
                        a0[ii][k], b1[jj][k], acc[ii][2 + jj], 0, 0, 0);
        __builtin_amdgcn_s_setprio(0);

        // ================= phase 2 (qr=1, qc=0) =================
        asm volatile("s_waitcnt vmcnt(4)" ::: "memory");
        __builtin_amdgcn_s_barrier();
        #pragma unroll
        for (int ii = 0; ii < 4; ++ii) {
            a1[ii][0] = *(const bf16x8*)(A1b + foff(ii, 0));
            a1[ii][1] = *(const bf16x8*)(A1b + foff(ii, 1));
        }
        if (t < 6) { stageA((t4 + 2) & 7, t + 2, 0); stageB((t4 + 2) & 7, t + 2, 0); }
        asm volatile("s_waitcnt lgkmcnt(0)" ::: "memory");
        __builtin_amdgcn_sched_barrier(0);
        __builtin_amdgcn_s_setprio(1);
        #pragma unroll
        for (int ii = 0; ii < 4; ++ii)
            #pragma unroll
            for (int jj = 0; jj < 2; ++jj)
                #pragma unroll
                for (int k = 0; k < 2; ++k)
                    acc[4 + ii][jj] = __builtin_amdgcn_mfma_f32_16x16x32_bf16(
                        a1[ii][k], b0[jj][k], acc[4 + ii][jj], 0, 0, 0);
        __builtin_amdgcn_s_setprio(0);

        // ================= phase 3 (qr=1, qc=1) =================
        asm volatile("s_waitcnt vmcnt(4)" ::: "memory");
        __builtin_amdgcn_s_barrier();
        if (t < 6) { stageA((t4 + 3) & 7, t + 2, 2); stageB((t4 + 3) & 7, t + 2, 1); }
        __builtin_amdgcn_s_setprio(1);
        #pragma unroll
        for (int ii = 0; ii < 4; ++ii)
            #pragma unroll
            for (int jj = 0; jj < 2; ++jj)
                #pragma unroll
                for (int k = 0; k < 2; ++k)
                    acc[4 + ii][2 + jj] = __builtin_amdgcn_mfma_f32_16x16x32_bf16(
                        a1[ii][k], b1[jj][k], acc[4 + ii][2 + jj], 0, 0, 0);
        __builtin_amdgcn_s_setprio(0);
    }

    // ---- epilogue: exp(2*sim), mask diag, row sums (+ col sums off-diag) ----
    __syncthreads();                    // all waves done with last ds_reads
    float* rs = (float*)&Aring[0][0];   // rowsum[256] | colsum[256]
    float* cs = rs + 256;
    if (tid < 256) { rs[tid] = 0.0f; cs[tid] = 0.0f; }
    __syncthreads();

    float colsum[4] = {0.0f, 0.0f, 0.0f, 0.0f};
    #pragma unroll
    for (int i = 0; i < 8; ++i) {
        #pragma unroll
        for (int r = 0; r < 4; ++r) {
            int lrow = wm + i * 16 + quad * 4 + r;    // local row 0..255
            int grow = rb + lrow;
            float s = 0.0f;
            #pragma unroll
            for (int j = 0; j < 4; ++j) {
                int gcol = cb + wn + j * 16 + m;
                float v  = __expf(2.0f * acc[i][j][r]);
                v = (grow == gcol) ? 0.0f : v;
                s += v;
                colsum[j] += v;
            }
            // sum across the 16 lanes of this quad-row group (bits 0..3)
            s += __shfl_xor(s, 1);
            s += __shfl_xor(s, 2);
            s += __shfl_xor(s, 4);
            s += __shfl_xor(s, 8);
            if (m == 0) atomicAdd(&rs[lrow], s);
        }
    }
    if (!diag) {
        #pragma unroll
        for (int j = 0; j < 4; ++j) {
            float s = colsum[j];       // this wave's 128 rows, col wn+j*16+m
            s += __shfl_xor(s, 16);    // combine across quads (rows)
            s += __shfl_xor(s, 32);
            if (quad == 0) atomicAdd(&cs[wn + j * 16 + m], s);
        }
    }
    __syncthreads();
    if (tid < 256) {
        atomicAdd(&denom[rb + tid], rs[tid]);
        if (!diag) atomicAdd(&denom[cb + tid], cs[tid]);
    }
}

// ---------------------------------------------------------------------------
// Kernel 3: loss += sum_r [ log(denom[r]) - 2*pos[r % N] ] / 2N.
// 32 blocks x 256 threads, one row each; per-block reduce + one atomic.
__global__ void loss_kernel(const float* __restrict__ pos,
                            const float* __restrict__ denom,
                            float* __restrict__ out) {
    int r = blockIdx.x * 256 + threadIdx.x;   // 0..8191
    float s = __logf(denom[r]) - 2.0f * pos[r & (N_ROWS - 1)];
    for (int o = 32; o; o >>= 1) s += __shfl_down(s, o);
    __shared__ float red[4];
    int t = threadIdx.x;
    if ((t & 63) == 0) red[t >> 6] = s;
    __syncthreads();
    if (t == 0)
        atomicAdd(out, (red[0] + red[1] + red[2] + red[3]) / (float)TWO_N);
}

// ---------------------------------------------------------------------------
extern "C" void kernel_launch(void* const* d_in, const int* in_sizes, int n_in,
                              void* d_out, int out_size, void* d_ws, size_t ws_size,
                              hipStream_t stream) {
    const float* ei = (const float*)d_in[0];
    const float* ej = (const float*)d_in[1];

    // ws layout: zb (bf16, 2N*D = 8 MB) | pos (N f32) | denom (2N f32)
    unsigned short* zb  = (unsigned short*)d_ws;
    float* pos   = (float*)((char*)d_ws + (size_t)TWO_N * DIM * sizeof(unsigned short));
    float* denom = pos + N_ROWS;
    float* out   = (float*)d_out;

    normalize_kernel<<<N_ROWS, 256, 0, stream>>>(ei, ej, zb, pos, denom, out);
    gemm_exp_kernel<<<NTRI2, 512, 0, stream>>>(zb, denom);
    loss_kernel<<<TWO_N / 256, 256, 0, stream>>>(pos, denom, out);
}